// Round 1
// baseline (260.008 us; speedup 1.0000x reference)
//
#include <hip/hip_runtime.h>
#include <hip/hip_bf16.h>

#define DDIM   128
#define NPAIRS 8128
#define NROWS  131072

typedef __attribute__((ext_vector_type(8))) short bf16x8;
typedef __attribute__((ext_vector_type(4))) float f32x4;

__device__ inline unsigned short f32_to_bf16_rne(float f) {
    unsigned u = __float_as_uint(f);
    u += 0x7fffu + ((u >> 16) & 1u);   // round-to-nearest-even (finite inputs)
    return (unsigned short)(u >> 16);
}

// ---------------------------------------------------------------------------
// Kernel 1: build R = prod of Givens rotations (identity-seeded), emit bf16
// B-fragments for mfma_f32_16x16x32_bf16.
// Thread t owns row t of R: step (i,j) touches only R[t][i], R[t][j] -> rows
// are independent, zero syncs in the main scan.
// LDS row stride 129 floats -> bank (t + c) % 32: conflict-free.
// ---------------------------------------------------------------------------
__global__ __launch_bounds__(128) void rbuild_kernel(
        const float* __restrict__ theta,
        unsigned short* __restrict__ bfrag) {
    __shared__ float  R[DDIM * (DDIM + 1)];
    __shared__ float2 cs[NPAIRS];

    const int t = threadIdx.x;

    // cos/sin table (pairs are triu_indices(128, k=1) in i-major order)
    for (int idx = t; idx < NPAIRS; idx += 128) {
        float th = theta[idx];
        cs[idx] = make_float2(cosf(th), sinf(th));
    }

    float* row = &R[t * (DDIM + 1)];
    for (int c = 0; c < DDIM; ++c) row[c] = (c == t) ? 1.0f : 0.0f;
    __syncthreads();   // cs table visibility

    int p = 0;
    for (int i = 0; i < DDIM - 1; ++i) {
        float ri = row[i];
        #pragma unroll 8
        for (int j = i + 1; j < DDIM; ++j, ++p) {
            float2 a = cs[p];          // wave-uniform LDS read -> broadcast
            float rj = row[j];
            row[j] = fmaf(a.y, ri, a.x * rj);      // s*xi + c*xj
            ri     = fmaf(a.x, ri, -(a.y * rj));   // c*xi - s*xj
        }
        row[i] = ri;
    }
    __syncthreads();   // emit reads other threads' rows

    // B-fragment layout for 16x16x32 bf16 MFMA:
    //   value = R[k][col], k = kstep*32 + (lane>>4)*8 + e, col = ntile*16 + (lane&15)
    //   flat  = ((ntile*4 + kstep)*64 + lane)*8 + e
    for (int oi = t; oi < DDIM * DDIM; oi += 128) {
        int e     = oi & 7;
        int lane  = (oi >> 3) & 63;
        int kstep = (oi >> 9) & 3;
        int ntile = oi >> 11;
        int k   = kstep * 32 + ((lane >> 4) << 3) + e;
        int col = ntile * 16 + (lane & 15);
        bfrag[oi] = f32_to_bf16_rne(R[k * (DDIM + 1) + col]);
    }
}

// ---------------------------------------------------------------------------
// Kernel 2: out = x @ R.  No LDS: A-fragments from contiguous fp32 loads of x
// (converted to bf16 in-register), B-fragments straight from L2-resident
// pre-swizzled bfrag.  Block = 4 waves x (32 rows x 128 cols) = 128 rows.
// ---------------------------------------------------------------------------
__global__ __launch_bounds__(256) void gemm_kernel(
        const float* __restrict__ x,
        const unsigned short* __restrict__ bfrag,
        float* __restrict__ out) {
    const int lane = threadIdx.x & 63;
    const int wave = threadIdx.x >> 6;
    const int lrow = lane & 15;
    const int lkhi = lane >> 4;
    const long brow = (long)blockIdx.x * 128 + wave * 32;

    f32x4 acc[2][8];
    #pragma unroll
    for (int m = 0; m < 2; ++m)
        #pragma unroll
        for (int n = 0; n < 8; ++n)
            acc[m][n] = (f32x4){0.0f, 0.0f, 0.0f, 0.0f};

    #pragma unroll
    for (int kstep = 0; kstep < 4; ++kstep) {
        const int k0 = kstep * 32 + lkhi * 8;
        bf16x8 afr[2];
        #pragma unroll
        for (int m = 0; m < 2; ++m) {
            const float* src = x + (brow + m * 16 + lrow) * (long)DDIM + k0;
            f32x4 lo = *reinterpret_cast<const f32x4*>(src);
            f32x4 hi = *reinterpret_cast<const f32x4*>(src + 4);
            union { bf16x8 v; unsigned short u[8]; } ua;
            #pragma unroll
            for (int e = 0; e < 4; ++e) {
                ua.u[e]     = f32_to_bf16_rne(lo[e]);
                ua.u[e + 4] = f32_to_bf16_rne(hi[e]);
            }
            afr[m] = ua.v;
        }
        #pragma unroll
        for (int n = 0; n < 8; ++n) {
            bf16x8 bfr = *reinterpret_cast<const bf16x8*>(
                bfrag + ((size_t)(n * 4 + kstep) * 64 + lane) * 8);
            acc[0][n] = __builtin_amdgcn_mfma_f32_16x16x32_bf16(afr[0], bfr, acc[0][n], 0, 0, 0);
            acc[1][n] = __builtin_amdgcn_mfma_f32_16x16x32_bf16(afr[1], bfr, acc[1][n], 0, 0, 0);
        }
    }

    // C/D layout (verified m89): row = (lane>>4)*4 + r, col = lane&15 per 16x16 tile
    #pragma unroll
    for (int m = 0; m < 2; ++m) {
        #pragma unroll
        for (int r = 0; r < 4; ++r) {
            const long orow = brow + m * 16 + lkhi * 4 + r;
            #pragma unroll
            for (int n = 0; n < 8; ++n) {
                out[orow * DDIM + n * 16 + lrow] = acc[m][n][r];
            }
        }
    }
}

extern "C" void kernel_launch(void* const* d_in, const int* in_sizes, int n_in,
                              void* d_out, int out_size, void* d_ws, size_t ws_size,
                              hipStream_t stream) {
    (void)in_sizes; (void)n_in; (void)out_size; (void)ws_size;
    const float* x     = (const float*)d_in[0];
    const float* theta = (const float*)d_in[1];
    // d_in[2] (pairs) is deterministic triu order; not needed on device.
    unsigned short* bfrag = (unsigned short*)d_ws;     // 32 KB
    float* out = (float*)d_out;

    rbuild_kernel<<<1, 128, 0, stream>>>(theta, bfrag);
    gemm_kernel<<<NROWS / 128, 256, 0, stream>>>(x, bfrag, out);
}

// Round 2
// 91.828 us; speedup vs baseline: 2.8315x; 2.8315x over previous
//
#include <hip/hip_runtime.h>
#include <hip/hip_bf16.h>

#define DDIM    128
#define NPAIRS  8128
#define NROWS   131072
#define NCHUNK  64
#define CPAIRS  (NPAIRS / NCHUNK)   // 127 pairs per chunk
#define MATELEM (DDIM * DDIM)       // 16384

typedef __attribute__((ext_vector_type(8))) short bf16x8;
typedef __attribute__((ext_vector_type(4))) float f32x4;

__device__ inline unsigned short f32_to_bf16_rne(float f) {
    unsigned u = __float_as_uint(f);
    u += 0x7fffu + ((u >> 16) & 1u);   // round-to-nearest-even (finite inputs)
    return (unsigned short)(u >> 16);
}

// ---------------------------------------------------------------------------
// Kernel 1: 64 blocks, block c builds M_c = prod of its 127 Givens rotations
// (identity-seeded), written bf16 row-major to chunks[c].
// Thread t owns row t (LDS, stride 129 -> bank (t+j)%32, 2-way = free).
// i runs are register-cached; (i,j) transitions are wave-uniform branches.
// ---------------------------------------------------------------------------
__global__ __launch_bounds__(128) void chunk_kernel(
        const float* __restrict__ theta,
        const int*   __restrict__ pairs,
        unsigned short* __restrict__ chunks) {
    __shared__ float  R[DDIM * (DDIM + 1)];
    __shared__ float2 cs[CPAIRS];
    __shared__ int2   ij[CPAIRS];

    const int t  = threadIdx.x;
    const int c  = blockIdx.x;
    const int p0 = c * CPAIRS;

    if (t < CPAIRS) {
        float th = theta[p0 + t];
        cs[t] = make_float2(cosf(th), sinf(th));
        ij[t] = make_int2(pairs[2 * (p0 + t)], pairs[2 * (p0 + t) + 1]);
    }
    float* row = &R[t * (DDIM + 1)];
    for (int q = 0; q < DDIM; ++q) row[q] = (q == t) ? 1.0f : 0.0f;
    __syncthreads();

    int   cur_i = ij[0].x;
    float ri    = row[cur_i];
    for (int p = 0; p < CPAIRS; ++p) {
        int2   v = ij[p];
        float2 a = cs[p];
        if (v.x != cur_i) {            // wave-uniform
            row[cur_i] = ri;
            cur_i = v.x;
            ri = row[cur_i];
        }
        float rj = row[v.y];
        row[v.y] = fmaf(a.y, ri, a.x * rj);      // s*xi + c*xj
        ri       = fmaf(a.x, ri, -(a.y * rj));   // c*xi - s*xj
    }
    row[cur_i] = ri;
    __syncthreads();

    unsigned short* dst = chunks + (size_t)c * MATELEM;
    for (int oi = t; oi < MATELEM; oi += 128)     // lane-coalesced
        dst[oi] = f32_to_bf16_rne(R[(oi >> 7) * (DDIM + 1) + (oi & 127)]);
}

// ---------------------------------------------------------------------------
// Kernel 2: pairwise combine, dst[b] = src[2b] . src[2b+1]  (left = earlier).
// One block (4 waves) per product; wave w does rows [w*32, w*32+32).
// All operands L2/L1-resident (32 KB each). emit_frag: final level writes R
// directly in the gemm's B-fragment order.
// ---------------------------------------------------------------------------
__global__ __launch_bounds__(256) void combine_kernel(
        const unsigned short* __restrict__ src,
        unsigned short* __restrict__ dst, int emit_frag) {
    const int lane = threadIdx.x & 63;
    const int wave = threadIdx.x >> 6;
    const int lrow = lane & 15;
    const int lkhi = lane >> 4;

    const unsigned short* A = src + (size_t)(2 * blockIdx.x) * MATELEM;
    const unsigned short* B = A + MATELEM;

    f32x4 acc[2][8];
    #pragma unroll
    for (int m = 0; m < 2; ++m)
        #pragma unroll
        for (int n = 0; n < 8; ++n)
            acc[m][n] = (f32x4){0.0f, 0.0f, 0.0f, 0.0f};

    #pragma unroll
    for (int kstep = 0; kstep < 4; ++kstep) {
        const int k0 = kstep * 32 + lkhi * 8;
        bf16x8 afr[2];
        #pragma unroll
        for (int m = 0; m < 2; ++m)
            afr[m] = *reinterpret_cast<const bf16x8*>(
                A + (size_t)(wave * 32 + m * 16 + lrow) * DDIM + k0);
        #pragma unroll
        for (int n = 0; n < 8; ++n) {
            union { bf16x8 v; unsigned short u[8]; } ub;
            #pragma unroll
            for (int e = 0; e < 8; ++e)
                ub.u[e] = B[(size_t)(k0 + e) * DDIM + n * 16 + lrow];
            acc[0][n] = __builtin_amdgcn_mfma_f32_16x16x32_bf16(afr[0], ub.v, acc[0][n], 0, 0, 0);
            acc[1][n] = __builtin_amdgcn_mfma_f32_16x16x32_bf16(afr[1], ub.v, acc[1][n], 0, 0, 0);
        }
    }

    if (!emit_frag) {
        unsigned short* out = dst + (size_t)blockIdx.x * MATELEM;
        #pragma unroll
        for (int m = 0; m < 2; ++m)
            #pragma unroll
            for (int r = 0; r < 4; ++r) {
                const int orow = wave * 32 + m * 16 + lkhi * 4 + r;
                #pragma unroll
                for (int n = 0; n < 8; ++n)
                    out[orow * DDIM + n * 16 + lrow] = f32_to_bf16_rne(acc[m][n][r]);
            }
    } else {
        // fragment slot for value R[k][col]:
        //   flat = ((col>>4)*4 + (k>>5))*512 + (((k>>3)&3)*16 + (col&15))*8 + (k&7)
        #pragma unroll
        for (int m = 0; m < 2; ++m)
            #pragma unroll
            for (int r = 0; r < 4; ++r) {
                const int k = wave * 32 + m * 16 + lkhi * 4 + r;
                #pragma unroll
                for (int n = 0; n < 8; ++n) {
                    const int col  = n * 16 + lrow;
                    const size_t flat =
                        ((size_t)((col >> 4) * 4 + (k >> 5)) * 64 +
                         ((k >> 3) & 3) * 16 + (col & 15)) * 8 + (k & 7);
                    dst[flat] = f32_to_bf16_rne(acc[m][n][r]);
                }
            }
    }
}

// ---------------------------------------------------------------------------
// Kernel 3: out = x @ R.  No LDS: A-fragments from contiguous fp32 loads of x
// (converted to bf16 in-register), B-fragments straight from L2-resident
// pre-swizzled bfrag.  Block = 4 waves x (32 rows x 128 cols) = 128 rows.
// ---------------------------------------------------------------------------
__global__ __launch_bounds__(256) void gemm_kernel(
        const float* __restrict__ x,
        const unsigned short* __restrict__ bfrag,
        float* __restrict__ out) {
    const int lane = threadIdx.x & 63;
    const int wave = threadIdx.x >> 6;
    const int lrow = lane & 15;
    const int lkhi = lane >> 4;
    const long brow = (long)blockIdx.x * 128 + wave * 32;

    f32x4 acc[2][8];
    #pragma unroll
    for (int m = 0; m < 2; ++m)
        #pragma unroll
        for (int n = 0; n < 8; ++n)
            acc[m][n] = (f32x4){0.0f, 0.0f, 0.0f, 0.0f};

    #pragma unroll
    for (int kstep = 0; kstep < 4; ++kstep) {
        const int k0 = kstep * 32 + lkhi * 8;
        bf16x8 afr[2];
        #pragma unroll
        for (int m = 0; m < 2; ++m) {
            const float* src = x + (brow + m * 16 + lrow) * (long)DDIM + k0;
            f32x4 lo = *reinterpret_cast<const f32x4*>(src);
            f32x4 hi = *reinterpret_cast<const f32x4*>(src + 4);
            union { bf16x8 v; unsigned short u[8]; } ua;
            #pragma unroll
            for (int e = 0; e < 4; ++e) {
                ua.u[e]     = f32_to_bf16_rne(lo[e]);
                ua.u[e + 4] = f32_to_bf16_rne(hi[e]);
            }
            afr[m] = ua.v;
        }
        #pragma unroll
        for (int n = 0; n < 8; ++n) {
            bf16x8 bfr = *reinterpret_cast<const bf16x8*>(
                bfrag + ((size_t)(n * 4 + kstep) * 64 + lane) * 8);
            acc[0][n] = __builtin_amdgcn_mfma_f32_16x16x32_bf16(afr[0], bfr, acc[0][n], 0, 0, 0);
            acc[1][n] = __builtin_amdgcn_mfma_f32_16x16x32_bf16(afr[1], bfr, acc[1][n], 0, 0, 0);
        }
    }

    // C/D layout (verified m89): row = (lane>>4)*4 + r, col = lane&15 per 16x16 tile
    #pragma unroll
    for (int m = 0; m < 2; ++m) {
        #pragma unroll
        for (int r = 0; r < 4; ++r) {
            const long orow = brow + m * 16 + lkhi * 4 + r;
            #pragma unroll
            for (int n = 0; n < 8; ++n) {
                out[orow * DDIM + n * 16 + lrow] = acc[m][n][r];
            }
        }
    }
}

extern "C" void kernel_launch(void* const* d_in, const int* in_sizes, int n_in,
                              void* d_out, int out_size, void* d_ws, size_t ws_size,
                              hipStream_t stream) {
    (void)in_sizes; (void)n_in; (void)out_size; (void)ws_size;
    const float* x     = (const float*)d_in[0];
    const float* theta = (const float*)d_in[1];
    const int*   pairs = (const int*)d_in[2];
    float* out = (float*)d_out;

    // ws layout (bf16 elements): bufA = 64 mats (2 MB), bufB = 32 mats (1 MB),
    // frag = 1 mat in B-fragment order (32 KB) at +3 MB.
    unsigned short* bufA = (unsigned short*)d_ws;
    unsigned short* bufB = bufA + (size_t)NCHUNK * MATELEM;
    unsigned short* frag = bufA + (size_t)(NCHUNK + NCHUNK / 2) * MATELEM;

    chunk_kernel<<<NCHUNK, 128, 0, stream>>>(theta, pairs, bufA);
    combine_kernel<<<32, 256, 0, stream>>>(bufA, bufB, 0);
    combine_kernel<<<16, 256, 0, stream>>>(bufB, bufA, 0);
    combine_kernel<<< 8, 256, 0, stream>>>(bufA, bufB, 0);
    combine_kernel<<< 4, 256, 0, stream>>>(bufB, bufA, 0);
    combine_kernel<<< 2, 256, 0, stream>>>(bufA, bufB, 0);
    combine_kernel<<< 1, 256, 0, stream>>>(bufB, frag, 1);
    gemm_kernel<<<NROWS / 128, 256, 0, stream>>>(x, frag, out);
}